// Round 8
// baseline (124.881 us; speedup 1.0000x reference)
//
#include <hip/hip_runtime.h>
#include <hip/hip_bf16.h>
#include <cstdint>

#define CH 128
#define NB 512          // coarse buckets (128 nodes each); N < 65536 for packing
#define SCHUNK 4096     // edges per scatter/hist block (nblk must stay <= 256 for k_scanbkt)

typedef __attribute__((ext_vector_type(8))) short short8;
typedef __attribute__((ext_vector_type(4))) float f32x4;

union FragU {
  uint4 u;
  short8 s;
  ushort h[8];
};

// ---------------- bf16 helpers ----------------
__device__ __forceinline__ float bf_lo(uint32_t u) { return __uint_as_float(u << 16); }
__device__ __forceinline__ float bf_hi(uint32_t u) { return __uint_as_float(u & 0xffff0000u); }
__device__ __forceinline__ uint32_t f2bf(float f) {  // RNE, result in low 16
  uint32_t u = __float_as_uint(f);
  u += 0x7fff + ((u >> 16) & 1);
  return u >> 16;
}

// ---------------- CSR build: contention-free counting sort ----------------
// 1) per-block LDS histogram -> counts[bucket * nblk + blk] + bucket totals;
//    extra blocks do W pre-pack.
__global__ __launch_bounds__(256) void k_histw(const int* __restrict__ dst, int* __restrict__ counts,
                                               int* __restrict__ btotal, int E, int nblk,
                                               const float* __restrict__ W1, const float* __restrict__ W2,
                                               ushort* __restrict__ wbuf) {
  int blk = blockIdx.x;
  if (blk >= nblk) {
    // ---- W pre-pack into MFMA fragment order (hi/lo bf16) ----
    int bb = blk - nblk;             // 0..127
    int which = bb >> 6;
    int idx = (bb & 63) * 256 + threadIdx.x;  // 0..16383
    const float* W = which ? W2 : W1;
    ushort* hi = wbuf + which * 32768;
    ushort* lo = hi + 16384;
    int k = idx >> 7, n = idx & 127;
    float w = W[idx];
    uint32_t hb = f2bf(w);
    uint32_t lb = f2bf(w - bf_lo(hb));
    int j = n >> 4, t = k >> 5, ln = (n & 15) | (((k >> 3) & 3) << 4), i = k & 7;
    int p = (j * 4 + t) * 512 + ln * 8 + i;
    hi[p] = (ushort)hb;
    lo[p] = (ushort)lb;
    return;
  }
  __shared__ int sh[NB];
  int t = threadIdx.x;
  for (int i = t; i < NB; i += 256) sh[i] = 0;
  __syncthreads();
  int base = blk * SCHUNK, lim = min(base + SCHUNK, E);
  for (int i = base + t; i < lim; i += 256) atomicAdd(&sh[dst[i] >> 7], 1);
  __syncthreads();
  for (int i = t; i < NB; i += 256) {
    counts[i * nblk + blk] = sh[i];
    if (sh[i]) atomicAdd(&btotal[i], sh[i]);
  }
}

// 2) one block per bucket: redundant scan of 512 bucket totals -> bucket base,
//    then local scan of this bucket's nblk per-block counts (in place).
__global__ __launch_bounds__(256) void k_scanbkt(int* __restrict__ counts, const int* __restrict__ btotal,
                                                 int* __restrict__ bbase, int nblk, int E) {
  __shared__ int sp[256];
  int b = blockIdx.x, t = threadIdx.x;
  int v0 = btotal[2 * t], v1 = btotal[2 * t + 1];
  sp[t] = v0 + v1;
  __syncthreads();
  for (int off = 1; off < 256; off <<= 1) {
    int add = (t >= off) ? sp[t - off] : 0;
    __syncthreads();
    sp[t] += add;
    __syncthreads();
  }
  int g = b >> 1;
  int base = ((g > 0) ? sp[g - 1] : 0) + ((b & 1) ? btotal[b - 1] : 0);
  __syncthreads();
  int c = (t < nblk) ? counts[b * nblk + t] : 0;
  sp[t] = c;
  __syncthreads();
  for (int off = 1; off < 256; off <<= 1) {
    int add = (t >= off) ? sp[t - off] : 0;
    __syncthreads();
    sp[t] += add;
    __syncthreads();
  }
  int excl = sp[t] - c;
  if (t < nblk) counts[b * nblk + t] = base + excl;
  if (t == 0) bbase[b] = base;
  if (b == 0 && t == 0) bbase[NB] = E;
}

// 3) scatter: block base from scanned counts, local rank via LDS atomics (no global atomics)
__global__ __launch_bounds__(256) void k_scatter3(const int* __restrict__ src, const int* __restrict__ dst,
                                                  const int* __restrict__ excl, uint32_t* __restrict__ packed,
                                                  int E, int nblk) {
  __shared__ int lcur[NB];
  int t = threadIdx.x, blk = blockIdx.x;
  for (int i = t; i < NB; i += 256) lcur[i] = excl[i * nblk + blk];
  __syncthreads();
  int base = blk * SCHUNK, lim = min(base + SCHUNK, E);
  for (int i = base + t; i < lim; i += 256) {
    int d = dst[i], s = src[i];
    int slot = atomicAdd(&lcur[d >> 7], 1);
    packed[slot] = (uint32_t)s | ((uint32_t)(d & 127) << 16);
  }
}

// 4) per-bucket local CSR build; emits csr_src, row_ptr, dinv
__global__ __launch_bounds__(256) void k_bucket(const uint32_t* __restrict__ packed, const int* __restrict__ bbase,
                                                int* __restrict__ csr_src, int* __restrict__ row_ptr,
                                                float* __restrict__ dinv, int N, int E, int nb) {
  __shared__ int hist[128];
  __shared__ int scan[128];
  __shared__ int cur[128];
  int b = blockIdx.x;
  int t = threadIdx.x;
  int base = bbase[b], end = bbase[b + 1];
  if (t < 128) hist[t] = 0;
  __syncthreads();
  for (int i = base + t; i < end; i += 256)
    atomicAdd(&hist[packed[i] >> 16], 1);
  __syncthreads();
  int v = (t < 128) ? hist[t] : 0;
  if (t < 128) scan[t] = v;
  __syncthreads();
  for (int off = 1; off < 128; off <<= 1) {
    int add = (t < 128 && t >= off) ? scan[t - off] : 0;
    __syncthreads();
    if (t < 128) scan[t] += add;
    __syncthreads();
  }
  if (t < 128) {
    int excl = scan[t] - v;
    cur[t] = excl;
    int node = b * 128 + t;
    if (node < N) {
      row_ptr[node] = base + excl;
      dinv[node] = rsqrtf((float)(v + 1));  // +1 self-loop
    }
    if (b == nb - 1 && t == 0) row_ptr[N] = E;
  }
  __syncthreads();
  for (int i = base + t; i < end; i += 256) {
    uint32_t p = packed[i];
    int slot = atomicAdd(&cur[p >> 16], 1);
    csr_src[base + slot] = (int)(p & 0xffffu);
  }
}

// ---------------- MFMA GEMM: h'[r] = (A[r] @ W) * dinv[r], bf16 out ----------------
__global__ __launch_bounds__(256) void k_gemm_mfma(const float* __restrict__ A,
                                                   const ushort* __restrict__ wpack,
                                                   const float* __restrict__ dinv,
                                                   ushort* __restrict__ Cp, int n) {
  const int lane = threadIdx.x & 63;
  const int gwave = (blockIdx.x * 256 + threadIdx.x) >> 6;
  const int rb = gwave * 32;
  if (rb >= n) return;
  const int lrow = lane & 15, lgrp = lane >> 4;
  const uint4* whi4 = (const uint4*)wpack;
  const uint4* wlo4 = (const uint4*)(wpack + 16384);

  const int r0 = rb + lrow, r1 = rb + 16 + lrow;
  const bool v0 = r0 < n, v1 = r1 < n;
  const int rc0 = v0 ? r0 : 0, rc1 = v1 ? r1 : 0;

  f32x4 acc0[8] = {};
  f32x4 acc1[8] = {};
  const uint4 zz = make_uint4(0, 0, 0, 0);

#pragma unroll
  for (int t = 0; t < 4; ++t) {
    FragU a0h, a0l, a1h, a1l;
    const float* ap0 = A + (size_t)rc0 * CH + t * 32 + lgrp * 8;
    const float* ap1 = A + (size_t)rc1 * CH + t * 32 + lgrp * 8;
    float4 xa = *(const float4*)ap0, xb = *(const float4*)(ap0 + 4);
    float4 ya = *(const float4*)ap1, yb = *(const float4*)(ap1 + 4);
    float xv[8] = {xa.x, xa.y, xa.z, xa.w, xb.x, xb.y, xb.z, xb.w};
    float yv[8] = {ya.x, ya.y, ya.z, ya.w, yb.x, yb.y, yb.z, yb.w};
#pragma unroll
    for (int i = 0; i < 8; ++i) {
      uint32_t h0 = f2bf(xv[i]);
      a0h.h[i] = (ushort)h0;
      a0l.h[i] = (ushort)f2bf(xv[i] - bf_lo(h0));
      uint32_t h1 = f2bf(yv[i]);
      a1h.h[i] = (ushort)h1;
      a1l.h[i] = (ushort)f2bf(yv[i] - bf_lo(h1));
    }
    if (!v0) { a0h.u = zz; a0l.u = zz; }
    if (!v1) { a1h.u = zz; a1l.u = zz; }
#pragma unroll
    for (int j = 0; j < 8; ++j) {
      FragU wh, wl;
      wh.u = whi4[(j * 4 + t) * 64 + lane];
      wl.u = wlo4[(j * 4 + t) * 64 + lane];
      acc0[j] = __builtin_amdgcn_mfma_f32_16x16x32_bf16(wh.s, a0h.s, acc0[j], 0, 0, 0);
      acc0[j] = __builtin_amdgcn_mfma_f32_16x16x32_bf16(wl.s, a0h.s, acc0[j], 0, 0, 0);
      acc0[j] = __builtin_amdgcn_mfma_f32_16x16x32_bf16(wh.s, a0l.s, acc0[j], 0, 0, 0);
      acc1[j] = __builtin_amdgcn_mfma_f32_16x16x32_bf16(wh.s, a1h.s, acc1[j], 0, 0, 0);
      acc1[j] = __builtin_amdgcn_mfma_f32_16x16x32_bf16(wl.s, a1h.s, acc1[j], 0, 0, 0);
      acc1[j] = __builtin_amdgcn_mfma_f32_16x16x32_bf16(wh.s, a1l.s, acc1[j], 0, 0, 0);
    }
  }

  if (v0) {
    float dv = dinv[r0];
#pragma unroll
    for (int j = 0; j < 8; ++j) {
      uint2 o;
      o.x = f2bf(acc0[j][0] * dv) | (f2bf(acc0[j][1] * dv) << 16);
      o.y = f2bf(acc0[j][2] * dv) | (f2bf(acc0[j][3] * dv) << 16);
      *(uint2*)&Cp[(size_t)r0 * CH + j * 16 + lgrp * 4] = o;
    }
  }
  if (v1) {
    float dv = dinv[r1];
#pragma unroll
    for (int j = 0; j < 8; ++j) {
      uint2 o;
      o.x = f2bf(acc1[j][0] * dv) | (f2bf(acc1[j][1] * dv) << 16);
      o.y = f2bf(acc1[j][2] * dv) | (f2bf(acc1[j][3] * dv) << 16);
      *(uint2*)&Cp[(size_t)r1 * CH + j * 16 + lgrp * 4] = o;
    }
  }
}

// ---------------- aggregation core (half-wave pair gather) ----------------
// lanes 0-31 gather even-indexed edges, lanes 32-63 odd-indexed; each lane owns
// channels [4*hl, 4*hl+4) (duplicated across halves); one shfl_xor merge per node.
__device__ __forceinline__ float4 agg_node2(const uint32_t* __restrict__ hp, const int* __restrict__ row_ptr,
                                            const int* __restrict__ csr, int v, int hl, int half) {
  const int wo = 2 * hl;  // dword offset within row
  uint2 su = *(const uint2*)&hp[(size_t)v * 64 + wo];
  float a0 = 0.f, a1 = 0.f, a2 = 0.f, a3 = 0.f;
  if (half == 0) {  // self term counted once
    a0 = bf_lo(su.x); a1 = bf_hi(su.x); a2 = bf_lo(su.y); a3 = bf_hi(su.y);
  }
  int j = __builtin_amdgcn_readfirstlane(row_ptr[v]);
  int end = __builtin_amdgcn_readfirstlane(row_ptr[v + 1]);
  int cnt = end - j;
  int npair = cnt >> 1;
  int p = 0;
  for (; p + 3 < npair; p += 4) {
    int i0 = csr[j + 2 * p + 0 + half];
    int i1 = csr[j + 2 * p + 2 + half];
    int i2 = csr[j + 2 * p + 4 + half];
    int i3 = csr[j + 2 * p + 6 + half];
    uint2 u0 = *(const uint2*)&hp[(size_t)i0 * 64 + wo];
    uint2 u1 = *(const uint2*)&hp[(size_t)i1 * 64 + wo];
    uint2 u2 = *(const uint2*)&hp[(size_t)i2 * 64 + wo];
    uint2 u3 = *(const uint2*)&hp[(size_t)i3 * 64 + wo];
    a0 += bf_lo(u0.x); a1 += bf_hi(u0.x); a2 += bf_lo(u0.y); a3 += bf_hi(u0.y);
    a0 += bf_lo(u1.x); a1 += bf_hi(u1.x); a2 += bf_lo(u1.y); a3 += bf_hi(u1.y);
    a0 += bf_lo(u2.x); a1 += bf_hi(u2.x); a2 += bf_lo(u2.y); a3 += bf_hi(u2.y);
    a0 += bf_lo(u3.x); a1 += bf_hi(u3.x); a2 += bf_lo(u3.y); a3 += bf_hi(u3.y);
  }
  for (; p < npair; ++p) {
    int i0 = csr[j + 2 * p + half];
    uint2 u0 = *(const uint2*)&hp[(size_t)i0 * 64 + wo];
    a0 += bf_lo(u0.x); a1 += bf_hi(u0.x); a2 += bf_lo(u0.y); a3 += bf_hi(u0.y);
  }
  if (cnt & 1) {
    int s = __builtin_amdgcn_readfirstlane(csr[end - 1]);
    uint2 u = *(const uint2*)&hp[(size_t)s * 64 + wo];
    if (half == 0) {
      a0 += bf_lo(u.x); a1 += bf_hi(u.x); a2 += bf_lo(u.y); a3 += bf_hi(u.y);
    }
  }
  a0 += __shfl_xor(a0, 32, 64);
  a1 += __shfl_xor(a1, 32, 64);
  a2 += __shfl_xor(a2, 32, 64);
  a3 += __shfl_xor(a3, 32, 64);
  return make_float4(a0, a1, a2, a3);
}

// ---------------- fused: agg1(+b1,relu) -> LDS -> @W2 -> h2' = h2*dinv (bf16) ----------------
// block = 256 threads = 4 waves; 32 nodes per block; LDS XOR-swizzled 32x128 bf16.
__global__ __launch_bounds__(256) void k_fused(const uint32_t* __restrict__ h1p, const int* __restrict__ row_ptr,
                                               const int* __restrict__ csr, const float* __restrict__ dinv,
                                               const float* __restrict__ b1,
                                               const ushort* __restrict__ wpack2,
                                               ushort* __restrict__ h2, int N) {
  __shared__ uint32_t sy[32 * 64];  // 32 rows x 128 bf16, word-swizzled
  const int w = threadIdx.x >> 6;
  const int lane = threadIdx.x & 63;
  const int hl = lane & 31;
  const int half = lane >> 5;
  const int vb = blockIdx.x * 32;
  float4 bb = *(const float4*)&b1[4 * hl];

  // ---- agg phase: each wave aggregates 8 nodes ----
  for (int q = 0; q < 8; ++q) {
    int lv = w * 8 + q;
    int v = vb + lv;
    uint32_t d0 = 0, d1 = 0;
    if (v < N) {
      float4 a = agg_node2(h1p, row_ptr, csr, v, hl, half);
      float dv = dinv[v];
      float o0 = fmaxf(fmaf(dv, a.x, bb.x), 0.f);
      float o1 = fmaxf(fmaf(dv, a.y, bb.y), 0.f);
      float o2 = fmaxf(fmaf(dv, a.z, bb.z), 0.f);
      float o3 = fmaxf(fmaf(dv, a.w, bb.w), 0.f);
      d0 = f2bf(o0) | (f2bf(o1) << 16);
      d1 = f2bf(o2) | (f2bf(o3) << 16);
    }
    int widx = 2 * hl + half;
    sy[lv * 64 + (widx ^ ((lv & 7) << 2))] = half ? d1 : d0;
  }
  __syncthreads();

  // ---- MFMA phase: 32x128 @ W2; wave w covers output cols [w*32, w*32+32) ----
  const int lrow = lane & 15, lgrp = lane >> 4;
  const uint4* whi4 = (const uint4*)wpack2;
  const uint4* wlo4 = (const uint4*)(wpack2 + 16384);

  FragU af[2][4];
#pragma unroll
  for (int rt = 0; rt < 2; ++rt) {
#pragma unroll
    for (int t = 0; t < 4; ++t) {
      int row = rt * 16 + lrow;
      int grp = (t * 4 + lgrp) ^ (row & 7);
      af[rt][t].u = *(const uint4*)&sy[row * 64 + grp * 4];
    }
  }

  f32x4 acc[2][2] = {};
#pragma unroll
  for (int jj = 0; jj < 2; ++jj) {
    int j = w * 2 + jj;
#pragma unroll
    for (int t = 0; t < 4; ++t) {
      FragU wh, wl;
      wh.u = whi4[(j * 4 + t) * 64 + lane];
      wl.u = wlo4[(j * 4 + t) * 64 + lane];
      acc[0][jj] = __builtin_amdgcn_mfma_f32_16x16x32_bf16(wh.s, af[0][t].s, acc[0][jj], 0, 0, 0);
      acc[0][jj] = __builtin_amdgcn_mfma_f32_16x16x32_bf16(wl.s, af[0][t].s, acc[0][jj], 0, 0, 0);
      acc[1][jj] = __builtin_amdgcn_mfma_f32_16x16x32_bf16(wh.s, af[1][t].s, acc[1][jj], 0, 0, 0);
      acc[1][jj] = __builtin_amdgcn_mfma_f32_16x16x32_bf16(wl.s, af[1][t].s, acc[1][jj], 0, 0, 0);
    }
  }

#pragma unroll
  for (int rt = 0; rt < 2; ++rt) {
    int r = vb + rt * 16 + lrow;
    if (r < N) {
      float dvr = dinv[r];
#pragma unroll
      for (int jj = 0; jj < 2; ++jj) {
        int j = w * 2 + jj;
        uint2 o;
        o.x = f2bf(acc[rt][jj][0] * dvr) | (f2bf(acc[rt][jj][1] * dvr) << 16);
        o.y = f2bf(acc[rt][jj][2] * dvr) | (f2bf(acc[rt][jj][3] * dvr) << 16);
        *(uint2*)&h2[(size_t)r * CH + j * 16 + lgrp * 4] = o;
      }
    }
  }
}

// ---------------- final aggregation: out[v] = relu(dv * (sum h2'[s] + h2'[v]) + b2), fp32 ----
__global__ __launch_bounds__(256) void k_agg2(const uint32_t* __restrict__ h2p, const int* __restrict__ row_ptr,
                                              const int* __restrict__ csr, const float* __restrict__ dinv,
                                              const float* __restrict__ b2, float* __restrict__ out, int n) {
  int vw = (blockIdx.x * 256 + threadIdx.x) >> 6;
  int lane = threadIdx.x & 63;
  if (vw >= n) return;
  int v = __builtin_amdgcn_readfirstlane(vw);
  int hl = lane & 31;
  int half = lane >> 5;
  float4 a = agg_node2(h2p, row_ptr, csr, v, hl, half);
  float dv = dinv[v];
  float4 bb = *(const float4*)&b2[4 * hl];
  float o0 = fmaxf(fmaf(dv, a.x, bb.x), 0.f);
  float o1 = fmaxf(fmaf(dv, a.y, bb.y), 0.f);
  float o2 = fmaxf(fmaf(dv, a.z, bb.z), 0.f);
  float o3 = fmaxf(fmaf(dv, a.w, bb.w), 0.f);
  float2 lo = make_float2(o0, o1), hi = make_float2(o2, o3);
  *(float2*)&out[(size_t)v * CH + 4 * hl + 2 * half] = half ? hi : lo;
}

// ---------------- launch ----------------

extern "C" void kernel_launch(void* const* d_in, const int* in_sizes, int n_in,
                              void* d_out, int out_size, void* d_ws, size_t ws_size,
                              hipStream_t stream) {
  const float* x  = (const float*)d_in[0];
  const int*   ei = (const int*)d_in[1];
  const float* W1 = (const float*)d_in[2];
  const float* b1 = (const float*)d_in[3];
  const float* W2 = (const float*)d_in[4];
  const float* b2 = (const float*)d_in[5];
  float* out = (float*)d_out;

  const int N = in_sizes[0] / CH;
  const int E = in_sizes[1] / 2;
  const int* src = ei;
  const int* dst = ei + E;
  const int nb = (N + 127) / 128;              // used coarse buckets (<= NB)
  const int nblk = (E + SCHUNK - 1) / SCHUNK;  // hist/scatter blocks (<= 256)
  const int total = NB * nblk;                 // counts array size

  char* ws = (char*)d_ws;
  size_t off = 0;
  auto alloc = [&](size_t bytes) -> void* {
    void* p = ws + off;
    off += (bytes + 255) & ~(size_t)255;
    return p;
  };
  int*      counts  = (int*)alloc((size_t)total * 4);     // scanned in place
  int*      btotal  = (int*)alloc(NB * 4);
  int*      bbase   = (int*)alloc((NB + 1) * 4);
  uint32_t* packed  = (uint32_t*)alloc((size_t)E * 4);
  int*      row_ptr = (int*)alloc((size_t)(N + 1) * 4);
  int*      csr_src = (int*)alloc((size_t)E * 4);
  float*    dinv    = (float*)alloc((size_t)N * 4);
  ushort*   wpack   = (ushort*)alloc(4 * 16384 * 2);       // [hi1|lo1|hi2|lo2]
  ushort*   h1      = (ushort*)alloc((size_t)N * CH * 2);  // bf16, dinv-scaled
  ushort*   h2      = (ushort*)alloc((size_t)N * CH * 2);  // bf16, dinv-scaled
  (void)ws_size;

  hipMemsetAsync(btotal, 0, NB * 4, stream);  // must re-zero every call (accumulated by atomics)

  k_histw<<<nblk + 128, 256, 0, stream>>>(dst, counts, btotal, E, nblk, W1, W2, wpack);
  k_scanbkt<<<NB, 256, 0, stream>>>(counts, btotal, bbase, nblk, E);
  k_scatter3<<<nblk, 256, 0, stream>>>(src, dst, counts, packed, E, nblk);
  k_bucket<<<nb, 256, 0, stream>>>(packed, bbase, csr_src, row_ptr, dinv, N, E, nb);

  const int waves = (N + 31) / 32;
  const int gG = (waves + 3) / 4;
  const int gF = (N + 31) / 32;
  const int gA = (N + 3) / 4;

  k_gemm_mfma<<<gG, 256, 0, stream>>>(x, wpack, dinv, h1, N);
  k_fused<<<gF, 256, 0, stream>>>((const uint32_t*)h1, row_ptr, csr_src, dinv, b1,
                                  wpack + 32768, h2, N);
  k_agg2<<<gA, 256, 0, stream>>>((const uint32_t*)h2, row_ptr, csr_src, dinv, b2, out, N);
}